// Round 3
// baseline (1336.055 us; speedup 1.0000x reference)
//
#include <hip/hip_runtime.h>
#include <cstdint>
#include <cstddef>

typedef short s16x8 __attribute__((ext_vector_type(8)));
typedef float f32x4 __attribute__((ext_vector_type(4)));

#define DEV __device__ __forceinline__

DEV uint16_t f2bf(float f) {
  uint32_t u = __builtin_bit_cast(uint32_t, f);
  return (uint16_t)((u + 0x7FFFu + ((u >> 16) & 1u)) >> 16);
}
DEV float bf2f(uint16_t h) {
  uint32_t u = ((uint32_t)h) << 16;
  return __builtin_bit_cast(float, u);
}

DEV f32x4 mfma16(s16x8 a, s16x8 b, f32x4 c) {
  return __builtin_amdgcn_mfma_f32_16x16x32_bf16(a, b, c, 0, 0, 0);
}

#define GL2LDS16(gp, lp) \
  __builtin_amdgcn_global_load_lds((const __attribute__((address_space(1))) void*)(gp), \
                                   (__attribute__((address_space(3))) void*)(lp), 16, 0, 0)

// ---------------- sentinel: ws too small -> fill output with 1e9 ----------------
__global__ void fill_kernel(float* __restrict__ p, int n) {
  const int i = blockIdx.x * 256 + threadIdx.x;
  if (i < n) p[i] = 1.0e9f;
}

// ---------------- CPB bias table: biasH[h][delta] = 16*sigmoid(table[delta][h]) ----------
__global__ void cpb_kernel(const float* __restrict__ w1, const float* __restrict__ b1,
                           const float* __restrict__ w2, float* __restrict__ biasH) {
  const int idx = blockIdx.x * 256 + threadIdx.x;  // 0..8191
  const int delta = idx >> 4;                      // 0..511 (511 unused)
  const int h = idx & 15;
  float t = (float)(delta - 255) * (8.0f / 255.0f);
  float sgn = (t > 0.f) ? 1.f : ((t < 0.f) ? -1.f : 0.f);
  const float rc = sgn * log2f(fabsf(t) + 1.0f) * (1.0f / 3.0f);  // /log2(8)
  float acc = 0.f;
  for (int k = 0; k < 512; ++k) {
    const float hv = fmaxf(fmaf(rc, w1[k], b1[k]), 0.f);
    acc = fmaf(hv, w2[h * 512 + k], acc);
  }
  biasH[h * 512 + delta] = 16.0f / (1.0f + expf(-acc));
}

// ---------------- qkv bias vector: [q_bias, 0, v_bias] ----------------
__global__ void qkvbias_kernel(const float* __restrict__ qb, const float* __restrict__ vb,
                               float* __restrict__ o) {
  const int i = blockIdx.x * 256 + threadIdx.x;
  if (i >= 3072) return;
  o[i] = (i < 1024) ? qb[i] : ((i < 2048) ? 0.f : vb[i - 2048]);
}

// ---------------- fp32 -> bf16 convert (n4 float4 groups) ----------------
__global__ void cvt_kernel(const float* __restrict__ s, uint16_t* __restrict__ d, int n4) {
  const int i = blockIdx.x * 256 + threadIdx.x;
  if (i >= n4) return;
  const float4 v = *(const float4*)(s + (size_t)i * 4);
  ushort4 u;
  u.x = f2bf(v.x); u.y = f2bf(v.y); u.z = f2bf(v.z); u.w = f2bf(v.w);
  *(ushort4*)(d + (size_t)i * 4) = u;
}

// ---------------- cyclic shift (-S) + bf16 convert ----------------
__global__ void shiftcvt_kernel(const float* __restrict__ x, uint16_t* __restrict__ xw) {
  const int idx4 = blockIdx.x * 256 + threadIdx.x;  // 16384*256 float4 groups
  const int t = idx4 >> 8;                          // token 0..16383
  const int c4 = idx4 & 255;
  const int b = t >> 13, p = t & 8191;
  const int sp = (p + 128) & 8191;  // roll(x, -S)
  const float4 v = *(const float4*)(x + (size_t)(b * 8192 + sp) * 1024 + c4 * 4);
  ushort4 u;
  u.x = f2bf(v.x); u.y = f2bf(v.y); u.z = f2bf(v.z); u.w = f2bf(v.w);
  *(ushort4*)(xw + (size_t)t * 1024 + c4 * 4) = u;
}

// ---------------- bf16 GEMM: C = A(MxK) * B^T (B stored NxK) ----------------
// MODE 1: bf16 out = gelu(acc+bias). MODE 2: bf16 out = acc+bias.
template <int MODE>
__global__ __launch_bounds__(256, 2) void gemm_bt(
    const uint16_t* __restrict__ A, const uint16_t* __restrict__ Bw,
    const float* __restrict__ bias, uint16_t* __restrict__ outB,
    int M, int N, int K) {
  __shared__ __align__(16) uint16_t As[4096];  // 128 rows x 32 k
  __shared__ __align__(16) uint16_t Bs[4096];
  const int tid = threadIdx.x;
  const int nTn = N >> 7;
  const int bm = blockIdx.x / nTn;
  const int bn = blockIdx.x - bm * nTn;
  const int lane = tid & 63;
  const int wid = tid >> 6;
  const int wr = (wid >> 1) * 64;
  const int wc = (wid & 1) * 64;

  const size_t aBase = (size_t)(bm * 128 + (tid >> 2)) * K + (size_t)(tid & 3) * 8;
  const size_t bBase = (size_t)(bn * 128 + (tid >> 2)) * K + (size_t)(tid & 3) * 8;
  const size_t half = (size_t)64 * K;
  uint16_t* lA = As + (size_t)wid * 512;  // wave-uniform base; HW adds lane*16B
  uint16_t* lB = Bs + (size_t)wid * 512;

  const f32x4 fzero = {0.f, 0.f, 0.f, 0.f};
  f32x4 acc[4][4];
#pragma unroll
  for (int m = 0; m < 4; ++m)
#pragma unroll
    for (int n = 0; n < 4; ++n) acc[m][n] = fzero;

  const int r16 = lane & 15;
  const int koff = (lane >> 4) * 8;

  for (int kt = 0; kt < K; kt += 32) {
    GL2LDS16(A + aBase + kt, lA);
    GL2LDS16(A + aBase + kt + half, lA + 2048);
    GL2LDS16(Bw + bBase + kt, lB);
    GL2LDS16(Bw + bBase + kt + half, lB + 2048);
    __syncthreads();
    s16x8 af[4], bfr[4];
#pragma unroll
    for (int m = 0; m < 4; ++m)
      af[m] = *(const s16x8*)(As + (wr + m * 16 + r16) * 32 + koff);
#pragma unroll
    for (int n = 0; n < 4; ++n)
      bfr[n] = *(const s16x8*)(Bs + (wc + n * 16 + r16) * 32 + koff);
#pragma unroll
    for (int m = 0; m < 4; ++m)
#pragma unroll
      for (int n = 0; n < 4; ++n)
        acc[m][n] = mfma16(af[m], bfr[n], acc[m][n]);
    __syncthreads();
  }

  const int row0 = bm * 128 + wr + (lane >> 4) * 4;
  const int col0 = bn * 128 + wc + r16;
#pragma unroll
  for (int m = 0; m < 4; ++m) {
#pragma unroll
    for (int n = 0; n < 4; ++n) {
      const int col = col0 + n * 16;
      const float bv = bias[col];
#pragma unroll
      for (int r = 0; r < 4; ++r) {
        const int row = row0 + m * 16 + r;
        float v = acc[m][n][r] + bv;
        if (MODE == 1) v = 0.5f * v * (1.f + erff(v * 0.70710678f));
        outB[(size_t)row * N + col] = f2bf(v);
      }
    }
  }
}

// ---------------- in-place l2 normalize of bf16 q,k rows (64-dim) ----------------
__global__ __launch_bounds__(256) void l2norm_kernel(uint16_t* __restrict__ qkv) {
  const int t = threadIdx.x;
  const int g = t >> 4, sub = t & 15;
  const int R = blockIdx.x * 16 + g;  // rows over 16384 tokens * {q,k} * 16 heads
  const int tok = R >> 5, rem = R & 31;
  const int qk = rem >> 4, h = rem & 15;
  uint16_t* p = qkv + (size_t)tok * 3072 + qk * 1024 + h * 64 + sub * 4;
  const ushort4 u = *(const ushort4*)p;
  float a = bf2f(u.x), b = bf2f(u.y), c = bf2f(u.z), d = bf2f(u.w);
  float ss = a * a + b * b + c * c + d * d;
#pragma unroll
  for (int m = 1; m < 16; m <<= 1) ss += __shfl_xor(ss, m);
  const float inv = 1.f / fmaxf(sqrtf(ss), 1e-12f);
  ushort4 o;
  o.x = f2bf(a * inv); o.y = f2bf(b * inv); o.z = f2bf(c * inv); o.w = f2bf(d * inv);
  *(ushort4*)p = o;
}

// ---------------- windowed cosine attention, one thread per query row ----------------
__global__ __launch_bounds__(256) void attn_kernel(
    const uint16_t* __restrict__ qkv, const float* __restrict__ logit_scale,
    const float* __restrict__ biasH, uint16_t* __restrict__ outB) {
  __shared__ __align__(16) uint16_t kn[4096];  // 64 x 64 bf16
  __shared__ __align__(16) uint16_t vn[4096];
  __shared__ float bsm[512];
  const int w = blockIdx.x >> 4;  // window 0..63
  const int h = blockIdx.x & 15;
  const int i = threadIdx.x;      // query row
  const bool lastwin = ((w & 31) == 31);
  const float scale = __expf(fminf(logit_scale[h], 4.60517018599f));  // ln(100)

  bsm[i] = biasH[h * 512 + i];
  bsm[i + 256] = biasH[h * 512 + 256 + i];

  float q[64];
  const s16x8* qp8 = (const s16x8*)(qkv + (size_t)(w * 256 + i) * 3072 + h * 64);
#pragma unroll
  for (int d8 = 0; d8 < 8; ++d8) {
    const s16x8 qv = qp8[d8];
#pragma unroll
    for (int e = 0; e < 8; ++e) q[d8 * 8 + e] = bf2f((uint16_t)qv[e]) * scale;
  }
  float o[64];
#pragma unroll
  for (int d = 0; d < 64; ++d) o[d] = 0.f;
  float mmax = -1e30f, msum = 0.f;

  for (int jc = 0; jc < 4; ++jc) {
    const int j0 = jc * 64;
    __syncthreads();  // previous chunk consumed (covers bsm on jc=0)
    const uint16_t* kb = qkv + (size_t)(w * 256 + j0) * 3072 + 1024 + h * 64;
#pragma unroll
    for (int it = 0; it < 4; ++it) {
      const int idx = i + it * 256;   // 0..1023 16B-units (k: 0..511, v: 512..1023)
      const int isV = idx >> 9;
      const int li = idx & 511;
      const int row = li >> 3, u8 = li & 7;
      const s16x8 vv = *(const s16x8*)(kb + (size_t)row * 3072 + isV * 1024 + u8 * 8);
      *(s16x8*)((isV ? vn : kn) + row * 64 + u8 * 8) = vv;
    }
    __syncthreads();
#pragma unroll 1
    for (int j = 0; j < 64; ++j) {
      const int jj = j0 + j;
      float dot = 0.f;
      const s16x8* kr = (const s16x8*)(kn + j * 64);
#pragma unroll
      for (int d8 = 0; d8 < 8; ++d8) {
        const s16x8 kv = kr[d8];
#pragma unroll
        for (int e = 0; e < 8; ++e) dot = fmaf(q[d8 * 8 + e], bf2f((uint16_t)kv[e]), dot);
      }
      float s = dot + bsm[i - jj + 255];
      if (lastwin && ((i >> 7) != (jj >> 7))) s -= 100.f;
      float p;
      if (s > mmax) {
        const float corr = __expf(mmax - s);
        msum *= corr;
#pragma unroll
        for (int d = 0; d < 64; ++d) o[d] *= corr;
        mmax = s;
        p = 1.f;
      } else {
        p = __expf(s - mmax);
      }
      msum += p;
      const s16x8* vr = (const s16x8*)(vn + j * 64);
#pragma unroll
      for (int d8 = 0; d8 < 8; ++d8) {
        const s16x8 vv = vr[d8];
#pragma unroll
        for (int e = 0; e < 8; ++e) o[d8 * 8 + e] = fmaf(p, bf2f((uint16_t)vv[e]), o[d8 * 8 + e]);
      }
    }
  }
  const float inv = 1.f / msum;
  uint16_t* op = outB + (size_t)(w * 256 + i) * 1024 + h * 64;
#pragma unroll
  for (int d4 = 0; d4 < 16; ++d4) {
    ushort4 u;
    u.x = f2bf(o[d4 * 4 + 0] * inv);
    u.y = f2bf(o[d4 * 4 + 1] * inv);
    u.z = f2bf(o[d4 * 4 + 2] * inv);
    u.w = f2bf(o[d4 * 4 + 3] * inv);
    *(ushort4*)(op + d4 * 4) = u;
  }
}

// ---------------- LayerNorm + residual (bf16 src) ----------------
// FIRST=1: src in shifted window domain -> un-shift (+S); write fp32 out + bf16 copy.
// FIRST=0: resid and outF may alias (row-wise read-then-write).
template <int FIRST>
__global__ __launch_bounds__(256) void ln_kernel(
    const uint16_t* __restrict__ src, const float* resid,
    const float* __restrict__ gam, const float* __restrict__ bet,
    float* outF, uint16_t* __restrict__ outB) {
  const int tok = blockIdx.x;
  const int t = threadIdx.x;
  size_t srow;
  if (FIRST) {
    const int b = tok >> 13, l = tok & 8191;
    srow = (size_t)(b * 8192 + ((l - 128) & 8191)) * 1024;  // roll(+S)
  } else {
    srow = (size_t)tok * 1024;
  }
  const ushort4 u = *(const ushort4*)(src + srow + t * 4);
  const float vv[4] = {bf2f(u.x), bf2f(u.y), bf2f(u.z), bf2f(u.w)};
  float s1 = vv[0] + vv[1] + vv[2] + vv[3];
  float s2 = vv[0] * vv[0] + vv[1] * vv[1] + vv[2] * vv[2] + vv[3] * vv[3];
#pragma unroll
  for (int m = 1; m < 64; m <<= 1) {
    s1 += __shfl_xor(s1, m);
    s2 += __shfl_xor(s2, m);
  }
  __shared__ float r1[4], r2[4];
  const int wid = t >> 6;
  if ((t & 63) == 0) { r1[wid] = s1; r2[wid] = s2; }
  __syncthreads();
  s1 = r1[0] + r1[1] + r1[2] + r1[3];
  s2 = r2[0] + r2[1] + r2[2] + r2[3];
  const float mu = s1 * 0.0009765625f;
  const float var = s2 * 0.0009765625f - mu * mu;
  const float rs = rsqrtf(var + 1e-5f);
  const float4 rv = *(const float4*)(resid + (size_t)tok * 1024 + t * 4);
  const float rr[4] = {rv.x, rv.y, rv.z, rv.w};
#pragma unroll
  for (int e = 0; e < 4; ++e) {
    const int c = t * 4 + e;
    const float y = (vv[e] - mu) * rs * gam[c] + bet[c];
    const float xo = rr[e] + y;
    outF[(size_t)tok * 1024 + c] = xo;
    if (FIRST) outB[(size_t)tok * 1024 + c] = f2bf(xo);
  }
}

// ---------------- launch ----------------
extern "C" void kernel_launch(void* const* d_in, const int* in_sizes, int n_in,
                              void* d_out, int out_size, void* d_ws, size_t ws_size,
                              hipStream_t stream) {
  const float* x = (const float*)d_in[0];
  const float* qkv_w = (const float*)d_in[1];
  const float* q_bias = (const float*)d_in[2];
  const float* v_bias = (const float*)d_in[3];
  const float* logit_sc = (const float*)d_in[4];
  const float* cpb_w1 = (const float*)d_in[5];
  const float* cpb_b1 = (const float*)d_in[6];
  const float* cpb_w2 = (const float*)d_in[7];
  const float* proj_w = (const float*)d_in[8];
  const float* proj_b = (const float*)d_in[9];
  const float* n1g = (const float*)d_in[10];
  const float* n1b = (const float*)d_in[11];
  const float* fc1_w = (const float*)d_in[12];
  const float* fc1_b = (const float*)d_in[13];
  const float* fc2_w = (const float*)d_in[14];
  const float* fc2_b = (const float*)d_in[15];
  const float* n2g = (const float*)d_in[16];
  const float* n2b = (const float*)d_in[17];

  // Workspace map (phase-aliased, peak ~184 MB). Lifetimes:
  //  [0,32M)    xw (A-B)      -> out2b (E-F)   -> hbuf[0:64M) (G-H)
  //  [32,128M)  qkvB (B-D)    -> (64,96M) tmpb (H-I)
  //  [128,160M) attnout (D-E) -> x1b (F-I)
  //  [160M+)    bf16 weights + tables
  //  d_out doubles as fp32 x1 (written by ln1, read+rewritten by ln2)
  char* ws = (char*)d_ws;
  uint16_t* xw      = (uint16_t*)(ws + 0);
  uint16_t* out2b   = (uint16_t*)(ws + 0);
  uint16_t* hbuf    = (uint16_t*)(ws + 0);
  uint16_t* qkvB    = (uint16_t*)(ws + 33554432);
  uint16_t* tmpb    = (uint16_t*)(ws + 67108864);
  uint16_t* attnout = (uint16_t*)(ws + 134217728);
  uint16_t* x1b     = (uint16_t*)(ws + 134217728);
  uint16_t* wqkv    = (uint16_t*)(ws + 167772160);
  uint16_t* wproj   = (uint16_t*)(ws + 174063616);
  uint16_t* wfc1    = (uint16_t*)(ws + 176160768);
  uint16_t* wfc2    = (uint16_t*)(ws + 184549376);
  float* qkvb       = (float*)(ws + 192937984);
  float* biasH      = (float*)(ws + 192950272);
  float* outp = (float*)d_out;

  if (ws_size < 192983040ULL) {  // diagnosable sentinel instead of silent zero
    fill_kernel<<<(out_size + 255) / 256, 256, 0, stream>>>(outp, out_size);
    return;
  }

  cpb_kernel<<<32, 256, 0, stream>>>(cpb_w1, cpb_b1, cpb_w2, biasH);
  qkvbias_kernel<<<12, 256, 0, stream>>>(q_bias, v_bias, qkvb);
  cvt_kernel<<<3072, 256, 0, stream>>>(qkv_w, wqkv, 786432);
  cvt_kernel<<<1024, 256, 0, stream>>>(proj_w, wproj, 262144);
  cvt_kernel<<<4096, 256, 0, stream>>>(fc1_w, wfc1, 1048576);
  cvt_kernel<<<4096, 256, 0, stream>>>(fc2_w, wfc2, 1048576);
  shiftcvt_kernel<<<16384, 256, 0, stream>>>(x, xw);

  gemm_bt<2><<<3072, 256, 0, stream>>>(xw, wqkv, qkvb, qkvB, 16384, 3072, 1024);
  l2norm_kernel<<<32768, 256, 0, stream>>>(qkvB);
  attn_kernel<<<1024, 256, 0, stream>>>(qkvB, logit_sc, biasH, attnout);
  gemm_bt<2><<<1024, 256, 0, stream>>>(attnout, wproj, proj_b, out2b, 16384, 1024, 1024);
  ln_kernel<1><<<16384, 256, 0, stream>>>(out2b, x, n1g, n1b, outp, x1b);
  // MLP in two M=8192 passes to keep hidden buffer at 64 MB
  for (int p = 0; p < 2; ++p) {
    const size_t ro = (size_t)p * 8192;
    gemm_bt<1><<<2048, 256, 0, stream>>>(x1b + ro * 1024, wfc1, fc1_b, hbuf, 8192, 4096, 1024);
    gemm_bt<2><<<512, 256, 0, stream>>>(hbuf, wfc2, fc2_b, tmpb + ro * 1024, 8192, 1024, 4096);
  }
  ln_kernel<0><<<16384, 256, 0, stream>>>(tmpb, outp, n2g, n2b, outp, nullptr);
}

// Round 9
// 970.125 us; speedup vs baseline: 1.3772x; 1.3772x over previous
//
#include <hip/hip_runtime.h>
#include <cstdint>
#include <cstddef>

typedef short s16x8 __attribute__((ext_vector_type(8)));
typedef float f32x4 __attribute__((ext_vector_type(4)));

#define DEV __device__ __forceinline__

DEV uint16_t f2bf(float f) {
  uint32_t u = __builtin_bit_cast(uint32_t, f);
  return (uint16_t)((u + 0x7FFFu + ((u >> 16) & 1u)) >> 16);
}
DEV float bf2f(uint16_t h) {
  uint32_t u = ((uint32_t)h) << 16;
  return __builtin_bit_cast(float, u);
}

DEV f32x4 mfma16(s16x8 a, s16x8 b, f32x4 c) {
  return __builtin_amdgcn_mfma_f32_16x16x32_bf16(a, b, c, 0, 0, 0);
}

#define GL2LDS16(gp, lp) \
  __builtin_amdgcn_global_load_lds((const __attribute__((address_space(1))) void*)(gp), \
                                   (__attribute__((address_space(3))) void*)(lp), 16, 0, 0)

// ---------------- sentinel: ws too small -> fill output with 1e9 ----------------
__global__ void fill_kernel(float* __restrict__ p, int n) {
  const int i = blockIdx.x * 256 + threadIdx.x;
  if (i < n) p[i] = 1.0e9f;
}

// ---------------- CPB bias table: biasH[h][delta] = 16*sigmoid(table[delta][h]) ----------
__global__ void cpb_kernel(const float* __restrict__ w1, const float* __restrict__ b1,
                           const float* __restrict__ w2, float* __restrict__ biasH) {
  const int idx = blockIdx.x * 256 + threadIdx.x;  // 0..8191
  const int delta = idx >> 4;                      // 0..511 (511 unused)
  const int h = idx & 15;
  float t = (float)(delta - 255) * (8.0f / 255.0f);
  float sgn = (t > 0.f) ? 1.f : ((t < 0.f) ? -1.f : 0.f);
  const float rc = sgn * log2f(fabsf(t) + 1.0f) * (1.0f / 3.0f);  // /log2(8)
  float acc = 0.f;
  for (int k = 0; k < 512; ++k) {
    const float hv = fmaxf(fmaf(rc, w1[k], b1[k]), 0.f);
    acc = fmaf(hv, w2[h * 512 + k], acc);
  }
  biasH[h * 512 + delta] = 16.0f / (1.0f + expf(-acc));
}

// ---------------- qkv bias vector: [q_bias, 0, v_bias] ----------------
__global__ void qkvbias_kernel(const float* __restrict__ qb, const float* __restrict__ vb,
                               float* __restrict__ o) {
  const int i = blockIdx.x * 256 + threadIdx.x;
  if (i >= 3072) return;
  o[i] = (i < 1024) ? qb[i] : ((i < 2048) ? 0.f : vb[i - 2048]);
}

// ---------------- fp32 -> bf16 convert (n4 float4 groups) ----------------
__global__ void cvt_kernel(const float* __restrict__ s, uint16_t* __restrict__ d, int n4) {
  const int i = blockIdx.x * 256 + threadIdx.x;
  if (i >= n4) return;
  const float4 v = *(const float4*)(s + (size_t)i * 4);
  ushort4 u;
  u.x = f2bf(v.x); u.y = f2bf(v.y); u.z = f2bf(v.z); u.w = f2bf(v.w);
  *(ushort4*)(d + (size_t)i * 4) = u;
}

// ---------------- cyclic shift (-S) + bf16 convert ----------------
__global__ void shiftcvt_kernel(const float* __restrict__ x, uint16_t* __restrict__ xw) {
  const int idx4 = blockIdx.x * 256 + threadIdx.x;  // 16384*256 float4 groups
  const int t = idx4 >> 8;                          // token 0..16383
  const int c4 = idx4 & 255;
  const int b = t >> 13, p = t & 8191;
  const int sp = (p + 128) & 8191;  // roll(x, -S)
  const float4 v = *(const float4*)(x + (size_t)(b * 8192 + sp) * 1024 + c4 * 4);
  ushort4 u;
  u.x = f2bf(v.x); u.y = f2bf(v.y); u.z = f2bf(v.z); u.w = f2bf(v.w);
  *(ushort4*)(xw + (size_t)t * 1024 + c4 * 4) = u;
}

// ---------------- bf16 GEMM: C = A(MxK) * B^T (B stored NxK) ----------------
// MODE 1: bf16 out = gelu(acc+bias). MODE 2: bf16 out = acc+bias.
// MODE 3 (qkv): cols<2048 -> outB stride 2048 (q,k); cols>=2048 -> vT[w*16+h][d][kv].
template <int MODE>
__global__ __launch_bounds__(256, 2) void gemm_bt(
    const uint16_t* __restrict__ A, const uint16_t* __restrict__ Bw,
    const float* __restrict__ bias, uint16_t* __restrict__ outB,
    uint16_t* __restrict__ vTout, int M, int N, int K) {
  __shared__ __align__(16) uint16_t As[4096];  // 128 rows x 32 k
  __shared__ __align__(16) uint16_t Bs[4096];
  const int tid = threadIdx.x;
  const int nTn = N >> 7;
  const int bm = blockIdx.x / nTn;
  const int bn = blockIdx.x - bm * nTn;
  const int lane = tid & 63;
  const int wid = tid >> 6;
  const int wr = (wid >> 1) * 64;
  const int wc = (wid & 1) * 64;

  const size_t aBase = (size_t)(bm * 128 + (tid >> 2)) * K + (size_t)(tid & 3) * 8;
  const size_t bBase = (size_t)(bn * 128 + (tid >> 2)) * K + (size_t)(tid & 3) * 8;
  const size_t half = (size_t)64 * K;
  uint16_t* lA = As + (size_t)wid * 512;  // wave-uniform base; HW adds lane*16B
  uint16_t* lB = Bs + (size_t)wid * 512;

  const f32x4 fzero = {0.f, 0.f, 0.f, 0.f};
  f32x4 acc[4][4];
#pragma unroll
  for (int m = 0; m < 4; ++m)
#pragma unroll
    for (int n = 0; n < 4; ++n) acc[m][n] = fzero;

  const int r16 = lane & 15;
  const int koff = (lane >> 4) * 8;

  for (int kt = 0; kt < K; kt += 32) {
    GL2LDS16(A + aBase + kt, lA);
    GL2LDS16(A + aBase + kt + half, lA + 2048);
    GL2LDS16(Bw + bBase + kt, lB);
    GL2LDS16(Bw + bBase + kt + half, lB + 2048);
    __syncthreads();
    s16x8 af[4], bfr[4];
#pragma unroll
    for (int m = 0; m < 4; ++m)
      af[m] = *(const s16x8*)(As + (wr + m * 16 + r16) * 32 + koff);
#pragma unroll
    for (int n = 0; n < 4; ++n)
      bfr[n] = *(const s16x8*)(Bs + (wc + n * 16 + r16) * 32 + koff);
#pragma unroll
    for (int m = 0; m < 4; ++m)
#pragma unroll
      for (int n = 0; n < 4; ++n)
        acc[m][n] = mfma16(af[m], bfr[n], acc[m][n]);
    __syncthreads();
  }

  const int row0 = bm * 128 + wr + (lane >> 4) * 4;
  const int col0 = bn * 128 + wc + r16;
  if (MODE == 3 && bn >= 16) {
    // V columns -> transposed write vT[(w*16+h)][d][kv], 4 consecutive kv per lane
#pragma unroll
    for (int m = 0; m < 4; ++m) {
      const int tokb = row0 + m * 16;            // kv0 = tokb&255 (mult of 4), w = tokb>>8
#pragma unroll
      for (int n = 0; n < 4; ++n) {
        const int col = col0 + n * 16;
        const float bv = bias[col];
        const int hh = (col - 2048) >> 6, dd = (col - 2048) & 63;
        ushort4 pk;
        pk.x = f2bf(acc[m][n][0] + bv);
        pk.y = f2bf(acc[m][n][1] + bv);
        pk.z = f2bf(acc[m][n][2] + bv);
        pk.w = f2bf(acc[m][n][3] + bv);
        *(ushort4*)(vTout + ((size_t)((tokb >> 8) * 16 + hh) * 64 + dd) * 256 + (tokb & 255)) = pk;
      }
    }
    return;
  }
  const int ostride = (MODE == 3) ? 2048 : N;
#pragma unroll
  for (int m = 0; m < 4; ++m) {
#pragma unroll
    for (int n = 0; n < 4; ++n) {
      const int col = col0 + n * 16;
      const float bv = bias[col];
#pragma unroll
      for (int r = 0; r < 4; ++r) {
        const int row = row0 + m * 16 + r;
        float v = acc[m][n][r] + bv;
        if (MODE == 1) v = 0.5f * v * (1.f + erff(v * 0.70710678f));
        outB[(size_t)row * ostride + col] = f2bf(v);
      }
    }
  }
}

// ---------------- in-place l2 normalize of bf16 q,k rows (64-dim), stride 2048 ----------
__global__ __launch_bounds__(256) void l2norm_kernel(uint16_t* __restrict__ qkB) {
  const int t = threadIdx.x;
  const int gg = t >> 4, sub = t & 15;
  const int R = blockIdx.x * 16 + gg;  // rows over 16384 tokens * {q,k} * 16 heads
  const int tok = R >> 5, rem = R & 31;
  const int qksel = rem >> 4, hh = rem & 15;
  uint16_t* p = qkB + (size_t)tok * 2048 + qksel * 1024 + hh * 64 + sub * 4;
  const ushort4 u = *(const ushort4*)p;
  float a = bf2f(u.x), b = bf2f(u.y), c = bf2f(u.z), d = bf2f(u.w);
  float ss = a * a + b * b + c * c + d * d;
#pragma unroll
  for (int m = 1; m < 16; m <<= 1) ss += __shfl_xor(ss, m);
  const float inv = 1.f / fmaxf(sqrtf(ss), 1e-12f);
  ushort4 o;
  o.x = f2bf(a * inv); o.y = f2bf(b * inv); o.z = f2bf(c * inv); o.w = f2bf(d * inv);
  *(ushort4*)p = o;
}

// ---------------- MFMA windowed attention ----------------
// Block = 4 waves = one (window, head). Wave wid owns q rows [wid*64, wid*64+64).
// K chunk (64 kv x 64 d) and V^T chunk (64 d x 64 kv) in LDS, padded stride 72 elems.
// S = Q.K^T via 16x16x32 MFMA; online softmax in regs; P via per-wave LDS; O += P.V.
__global__ __launch_bounds__(256, 2) void attn_mfma(
    const uint16_t* __restrict__ qk, const uint16_t* __restrict__ vT,
    const float* __restrict__ logit_scale, const float* __restrict__ biasH,
    uint16_t* __restrict__ outB) {
  __shared__ __align__(16) uint16_t Ks[64 * 72];
  __shared__ __align__(16) uint16_t Vs[64 * 72];
  __shared__ __align__(16) uint16_t Ps[4][64 * 72];
  __shared__ float bsm[512];
  const int w = blockIdx.x >> 4;
  const int h = blockIdx.x & 15;
  const int tid = threadIdx.x;
  const int lane = tid & 63;
  const int wid = tid >> 6;
  const int q15 = lane & 15;
  const int g = lane >> 4;
  const bool lastwin = ((w & 31) == 31);
  const float scale = __expf(fminf(logit_scale[h], 4.60517018599f));  // ln(100)

  bsm[tid] = biasH[h * 512 + tid];
  bsm[tid + 256] = biasH[h * 512 + 256 + tid];

  // Q A-fragments: rows wid*64 + m*16 + q15, k-elems ks*32 + g*8 + e
  s16x8 qf[4][2];
  {
    const uint16_t* qb = qk + (size_t)(w * 256 + wid * 64 + q15) * 2048 + h * 64 + g * 8;
#pragma unroll
    for (int m = 0; m < 4; ++m)
#pragma unroll
      for (int ks = 0; ks < 2; ++ks)
        qf[m][ks] = *(const s16x8*)(qb + (size_t)(m * 16) * 2048 + ks * 32);
  }

  // staging addresses (2 x 16B units per thread for each of K, V^T)
  const int r0 = tid >> 3, c8 = (tid & 7) * 8;
  const uint16_t* kg = qk + (size_t)(w * 256 + r0) * 2048 + 1024 + h * 64 + c8;
  const uint16_t* vg = vT + ((size_t)(w * 16 + h) * 64 + r0) * 256 + c8;
  uint16_t* kd0 = Ks + r0 * 72 + c8;
  uint16_t* kd1 = Ks + (r0 + 32) * 72 + c8;
  uint16_t* vd0 = Vs + r0 * 72 + c8;
  uint16_t* vd1 = Vs + (r0 + 32) * 72 + c8;

  // chunk 0 stage
  s16x8 stK0 = *(const s16x8*)(kg);
  s16x8 stK1 = *(const s16x8*)(kg + 32 * 2048);
  s16x8 stV0 = *(const s16x8*)(vg);
  s16x8 stV1 = *(const s16x8*)(vg + 32 * 256);
  *(s16x8*)kd0 = stK0; *(s16x8*)kd1 = stK1;
  *(s16x8*)vd0 = stV0; *(s16x8*)vd1 = stV1;

  const f32x4 fzero = {0.f, 0.f, 0.f, 0.f};
  f32x4 o[4][4];
  float mrun[4][4], lrun[4][4];
#pragma unroll
  for (int m = 0; m < 4; ++m)
#pragma unroll
    for (int n = 0; n < 4; ++n) o[m][n] = fzero;
#pragma unroll
  for (int m = 0; m < 4; ++m)
#pragma unroll
    for (int r = 0; r < 4; ++r) { mrun[m][r] = -1e30f; lrun[m][r] = 0.f; }

  __syncthreads();

  for (int c = 0; c < 4; ++c) {
    if (c < 3) {  // T14: issue next-chunk loads early, write after barrier
      stK0 = *(const s16x8*)(kg + (size_t)(c + 1) * 64 * 2048);
      stK1 = *(const s16x8*)(kg + (size_t)(c + 1) * 64 * 2048 + 32 * 2048);
      stV0 = *(const s16x8*)(vg + (c + 1) * 64);
      stV1 = *(const s16x8*)(vg + (c + 1) * 64 + 32 * 256);
    }
    // K B-frags: col kv = n*16+q15, k-elems d = ks*32+g*8+e
    s16x8 kf[4][2];
#pragma unroll
    for (int n = 0; n < 4; ++n)
#pragma unroll
      for (int ks = 0; ks < 2; ++ks)
        kf[n][ks] = *(const s16x8*)(Ks + (n * 16 + q15) * 72 + ks * 32 + g * 8);

    f32x4 s[4][4];
#pragma unroll
    for (int m = 0; m < 4; ++m)
#pragma unroll
      for (int n = 0; n < 4; ++n) {
        f32x4 a = fzero;
        a = mfma16(qf[m][0], kf[n][0], a);
        a = mfma16(qf[m][1], kf[n][1], a);
        s[m][n] = a;
      }

    // scale + bias + shift-mask  (i row, j col within window)
#pragma unroll
    for (int m = 0; m < 4; ++m)
#pragma unroll
      for (int n = 0; n < 4; ++n)
#pragma unroll
        for (int r = 0; r < 4; ++r) {
          const int i = wid * 64 + m * 16 + g * 4 + r;
          const int j = c * 64 + n * 16 + q15;
          float sv = s[m][n][r] * scale + bsm[i - j + 255];
          if (lastwin && ((i >> 7) != (j >> 7))) sv -= 100.f;
          s[m][n][r] = sv;
        }

    // online softmax per row (m,r); row replicated across 16 lanes sharing g
#pragma unroll
    for (int m = 0; m < 4; ++m)
#pragma unroll
      for (int r = 0; r < 4; ++r) {
        float cm = fmaxf(fmaxf(s[m][0][r], s[m][1][r]), fmaxf(s[m][2][r], s[m][3][r]));
        cm = fmaxf(cm, __shfl_xor(cm, 1));
        cm = fmaxf(cm, __shfl_xor(cm, 2));
        cm = fmaxf(cm, __shfl_xor(cm, 4));
        cm = fmaxf(cm, __shfl_xor(cm, 8));
        const float mn = fmaxf(mrun[m][r], cm);
        const float corr = __expf(mrun[m][r] - mn);
        mrun[m][r] = mn;
        float rs = 0.f;
#pragma unroll
        for (int n = 0; n < 4; ++n) {
          const float p = __expf(s[m][n][r] - mn);
          s[m][n][r] = p;
          rs += p;
        }
        rs += __shfl_xor(rs, 1);
        rs += __shfl_xor(rs, 2);
        rs += __shfl_xor(rs, 4);
        rs += __shfl_xor(rs, 8);
        lrun[m][r] = lrun[m][r] * corr + rs;
#pragma unroll
        for (int nf = 0; nf < 4; ++nf) o[m][nf][r] *= corr;
      }

    // P -> per-wave LDS (bf16), then read as A-frags
    uint16_t* pw = Ps[wid];
#pragma unroll
    for (int m = 0; m < 4; ++m)
#pragma unroll
      for (int r = 0; r < 4; ++r)
#pragma unroll
        for (int n = 0; n < 4; ++n)
          pw[(m * 16 + g * 4 + r) * 72 + n * 16 + q15] = f2bf(s[m][n][r]);

    s16x8 pf[4][2], vf[4][2];
#pragma unroll
    for (int m = 0; m < 4; ++m)
#pragma unroll
      for (int ks = 0; ks < 2; ++ks)
        pf[m][ks] = *(const s16x8*)(pw + (m * 16 + q15) * 72 + ks * 32 + g * 8);
#pragma unroll
    for (int nf = 0; nf < 4; ++nf)
#pragma unroll
      for (int ks = 0; ks < 2; ++ks)
        vf[nf][ks] = *(const s16x8*)(Vs + (nf * 16 + q15) * 72 + ks * 32 + g * 8);
#pragma unroll
    for (int m = 0; m < 4; ++m)
#pragma unroll
      for (int nf = 0; nf < 4; ++nf) {
        o[m][nf] = mfma16(pf[m][0], vf[nf][0], o[m][nf]);
        o[m][nf] = mfma16(pf[m][1], vf[nf][1], o[m][nf]);
      }
    __syncthreads();
    if (c < 3) {
      *(s16x8*)kd0 = stK0; *(s16x8*)kd1 = stK1;
      *(s16x8*)vd0 = stV0; *(s16x8*)vd1 = stV1;
      __syncthreads();
    }
  }

  // epilogue: O /= l, store bf16
  uint16_t* ob = outB + (size_t)(w * 256 + wid * 64) * 1024 + h * 64;
#pragma unroll
  for (int m = 0; m < 4; ++m)
#pragma unroll
    for (int r = 0; r < 4; ++r) {
      const float inv = 1.f / lrun[m][r];
#pragma unroll
      for (int nf = 0; nf < 4; ++nf)
        ob[(size_t)(m * 16 + g * 4 + r) * 1024 + nf * 16 + q15] = f2bf(o[m][nf][r] * inv);
    }
}

// ---------------- LayerNorm + residual (bf16 src) ----------------
// FIRST=1: src in shifted window domain -> un-shift (+S); write fp32 out + bf16 copy.
// FIRST=0: resid and outF may alias (row-wise read-then-write).
template <int FIRST>
__global__ __launch_bounds__(256) void ln_kernel(
    const uint16_t* __restrict__ src, const float* resid,
    const float* __restrict__ gam, const float* __restrict__ bet,
    float* outF, uint16_t* __restrict__ outB) {
  const int tok = blockIdx.x;
  const int t = threadIdx.x;
  size_t srow;
  if (FIRST) {
    const int b = tok >> 13, l = tok & 8191;
    srow = (size_t)(b * 8192 + ((l - 128) & 8191)) * 1024;  // roll(+S)
  } else {
    srow = (size_t)tok * 1024;
  }
  const ushort4 u = *(const ushort4*)(src + srow + t * 4);
  const float vv[4] = {bf2f(u.x), bf2f(u.y), bf2f(u.z), bf2f(u.w)};
  float s1 = vv[0] + vv[1] + vv[2] + vv[3];
  float s2 = vv[0] * vv[0] + vv[1] * vv[1] + vv[2] * vv[2] + vv[3] * vv[3];
#pragma unroll
  for (int m = 1; m < 64; m <<= 1) {
    s1 += __shfl_xor(s1, m);
    s2 += __shfl_xor(s2, m);
  }
  __shared__ float r1[4], r2[4];
  const int wid = t >> 6;
  if ((t & 63) == 0) { r1[wid] = s1; r2[wid] = s2; }
  __syncthreads();
  s1 = r1[0] + r1[1] + r1[2] + r1[3];
  s2 = r2[0] + r2[1] + r2[2] + r2[3];
  const float mu = s1 * 0.0009765625f;
  const float var = s2 * 0.0009765625f - mu * mu;
  const float rs = rsqrtf(var + 1e-5f);
  const float4 rv = *(const float4*)(resid + (size_t)tok * 1024 + t * 4);
  const float rr[4] = {rv.x, rv.y, rv.z, rv.w};
#pragma unroll
  for (int e = 0; e < 4; ++e) {
    const int c = t * 4 + e;
    const float y = (vv[e] - mu) * rs * gam[c] + bet[c];
    const float xo = rr[e] + y;
    outF[(size_t)tok * 1024 + c] = xo;
    if (FIRST) outB[(size_t)tok * 1024 + c] = f2bf(xo);
  }
}

// ---------------- launch ----------------
extern "C" void kernel_launch(void* const* d_in, const int* in_sizes, int n_in,
                              void* d_out, int out_size, void* d_ws, size_t ws_size,
                              hipStream_t stream) {
  const float* x = (const float*)d_in[0];
  const float* qkv_w = (const float*)d_in[1];
  const float* q_bias = (const float*)d_in[2];
  const float* v_bias = (const float*)d_in[3];
  const float* logit_sc = (const float*)d_in[4];
  const float* cpb_w1 = (const float*)d_in[5];
  const float* cpb_b1 = (const float*)d_in[6];
  const float* cpb_w2 = (const float*)d_in[7];
  const float* proj_w = (const float*)d_in[8];
  const float* proj_b = (const float*)d_in[9];
  const float* n1g = (const float*)d_in[10];
  const float* n1b = (const float*)d_in[11];
  const float* fc1_w = (const float*)d_in[12];
  const float* fc1_b = (const float*)d_in[13];
  const float* fc2_w = (const float*)d_in[14];
  const float* fc2_b = (const float*)d_in[15];
  const float* n2g = (const float*)d_in[16];
  const float* n2b = (const float*)d_in[17];

  // Workspace map (phase-aliased, peak ~193 MB). Lifetimes:
  //  [0,64M)    qkB (B-D)      -> out2b [0,32M) (E-F) -> hbuf [0,64M) (G-H)
  //  [64,96M)   vT (B-D)       -> x1b (F-I)
  //  [96,128M)  xw (A-B)       -> attnout (D-E)
  //  [128,160M) tmpb (H-I)
  //  [160M+)    bf16 weights + tables
  //  d_out doubles as fp32 x1 (written by ln1, read+rewritten by ln2)
  char* ws = (char*)d_ws;
  uint16_t* qkB     = (uint16_t*)(ws + 0);
  uint16_t* out2b   = (uint16_t*)(ws + 0);
  uint16_t* hbuf    = (uint16_t*)(ws + 0);
  uint16_t* vT      = (uint16_t*)(ws + 67108864);
  uint16_t* x1b     = (uint16_t*)(ws + 67108864);
  uint16_t* xw      = (uint16_t*)(ws + 100663296);
  uint16_t* attnout = (uint16_t*)(ws + 100663296);
  uint16_t* tmpb    = (uint16_t*)(ws + 134217728);
  uint16_t* wqkv    = (uint16_t*)(ws + 167772160);
  uint16_t* wproj   = (uint16_t*)(ws + 174063616);
  uint16_t* wfc1    = (uint16_t*)(ws + 176160768);
  uint16_t* wfc2    = (uint16_t*)(ws + 184549376);
  float* qkvb       = (float*)(ws + 192937984);
  float* biasH      = (float*)(ws + 192950272);
  float* outp = (float*)d_out;

  if (ws_size < 192983040ULL) {  // diagnosable sentinel instead of silent zero
    fill_kernel<<<(out_size + 255) / 256, 256, 0, stream>>>(outp, out_size);
    return;
  }

  cpb_kernel<<<32, 256, 0, stream>>>(cpb_w1, cpb_b1, cpb_w2, biasH);
  qkvbias_kernel<<<12, 256, 0, stream>>>(q_bias, v_bias, qkvb);
  cvt_kernel<<<3072, 256, 0, stream>>>(qkv_w, wqkv, 786432);
  cvt_kernel<<<1024, 256, 0, stream>>>(proj_w, wproj, 262144);
  cvt_kernel<<<4096, 256, 0, stream>>>(fc1_w, wfc1, 1048576);
  cvt_kernel<<<4096, 256, 0, stream>>>(fc2_w, wfc2, 1048576);
  shiftcvt_kernel<<<16384, 256, 0, stream>>>(x, xw);

  gemm_bt<3><<<3072, 256, 0, stream>>>(xw, wqkv, qkvb, qkB, vT, 16384, 3072, 1024);
  l2norm_kernel<<<32768, 256, 0, stream>>>(qkB);
  attn_mfma<<<1024, 256, 0, stream>>>(qkB, vT, logit_sc, biasH, attnout);
  gemm_bt<2><<<1024, 256, 0, stream>>>(attnout, wproj, proj_b, out2b, nullptr, 16384, 1024, 1024);
  ln_kernel<1><<<16384, 256, 0, stream>>>(out2b, x, n1g, n1b, outp, x1b);
  // MLP in two M=8192 passes to keep hidden buffer at 64 MB
  for (int p = 0; p < 2; ++p) {
    const size_t ro = (size_t)p * 8192;
    gemm_bt<1><<<2048, 256, 0, stream>>>(x1b + ro * 1024, wfc1, fc1_b, hbuf, nullptr, 8192, 4096, 1024);
    gemm_bt<2><<<512, 256, 0, stream>>>(hbuf, wfc2, fc2_b, tmpb + ro * 1024, nullptr, 8192, 1024, 4096);
  }
  ln_kernel<0><<<16384, 256, 0, stream>>>(tmpb, outp, n2g, n2b, outp, nullptr);
}

// Round 10
// 929.895 us; speedup vs baseline: 1.4368x; 1.0433x over previous
//
#include <hip/hip_runtime.h>
#include <cstdint>
#include <cstddef>

typedef short s16x8 __attribute__((ext_vector_type(8)));
typedef float f32x4 __attribute__((ext_vector_type(4)));

#define DEV __device__ __forceinline__

DEV uint16_t f2bf(float f) {
  uint32_t u = __builtin_bit_cast(uint32_t, f);
  return (uint16_t)((u + 0x7FFFu + ((u >> 16) & 1u)) >> 16);
}
DEV float bf2f(uint16_t h) {
  uint32_t u = ((uint32_t)h) << 16;
  return __builtin_bit_cast(float, u);
}

DEV f32x4 mfma16(s16x8 a, s16x8 b, f32x4 c) {
  return __builtin_amdgcn_mfma_f32_16x16x32_bf16(a, b, c, 0, 0, 0);
}

#define GL2LDS16(gp, lp) \
  __builtin_amdgcn_global_load_lds((const __attribute__((address_space(1))) void*)(gp), \
                                   (__attribute__((address_space(3))) void*)(lp), 16, 0, 0)

// ---------------- sentinel: ws too small -> fill output with 1e9 ----------------
__global__ void fill_kernel(float* __restrict__ p, int n) {
  const int i = blockIdx.x * 256 + threadIdx.x;
  if (i < n) p[i] = 1.0e9f;
}

// ---------------- CPB bias table: biasH[h][delta] = 16*sigmoid(table[delta][h]) ----------
__global__ void cpb_kernel(const float* __restrict__ w1, const float* __restrict__ b1,
                           const float* __restrict__ w2, float* __restrict__ biasH) {
  const int idx = blockIdx.x * 256 + threadIdx.x;  // 0..8191
  const int delta = idx >> 4;                      // 0..511 (511 unused)
  const int h = idx & 15;
  float t = (float)(delta - 255) * (8.0f / 255.0f);
  float sgn = (t > 0.f) ? 1.f : ((t < 0.f) ? -1.f : 0.f);
  const float rc = sgn * log2f(fabsf(t) + 1.0f) * (1.0f / 3.0f);  // /log2(8)
  float acc = 0.f;
  for (int k = 0; k < 512; ++k) {
    const float hv = fmaxf(fmaf(rc, w1[k], b1[k]), 0.f);
    acc = fmaf(hv, w2[h * 512 + k], acc);
  }
  biasH[h * 512 + delta] = 16.0f / (1.0f + expf(-acc));
}

// ---------------- qkv bias vector: [q_bias, 0, v_bias] ----------------
__global__ void qkvbias_kernel(const float* __restrict__ qb, const float* __restrict__ vb,
                               float* __restrict__ o) {
  const int i = blockIdx.x * 256 + threadIdx.x;
  if (i >= 3072) return;
  o[i] = (i < 1024) ? qb[i] : ((i < 2048) ? 0.f : vb[i - 2048]);
}

// ---------------- fp32 -> bf16 convert (n4 float4 groups) ----------------
__global__ void cvt_kernel(const float* __restrict__ s, uint16_t* __restrict__ d, int n4) {
  const int i = blockIdx.x * 256 + threadIdx.x;
  if (i >= n4) return;
  const float4 v = *(const float4*)(s + (size_t)i * 4);
  ushort4 u;
  u.x = f2bf(v.x); u.y = f2bf(v.y); u.z = f2bf(v.z); u.w = f2bf(v.w);
  *(ushort4*)(d + (size_t)i * 4) = u;
}

// ---------------- cyclic shift (-S) + bf16 convert ----------------
__global__ void shiftcvt_kernel(const float* __restrict__ x, uint16_t* __restrict__ xw) {
  const int idx4 = blockIdx.x * 256 + threadIdx.x;  // 16384*256 float4 groups
  const int t = idx4 >> 8;                          // token 0..16383
  const int c4 = idx4 & 255;
  const int b = t >> 13, p = t & 8191;
  const int sp = (p + 128) & 8191;  // roll(x, -S)
  const float4 v = *(const float4*)(x + (size_t)(b * 8192 + sp) * 1024 + c4 * 4);
  ushort4 u;
  u.x = f2bf(v.x); u.y = f2bf(v.y); u.z = f2bf(v.z); u.w = f2bf(v.w);
  *(ushort4*)(xw + (size_t)t * 1024 + c4 * 4) = u;
}

// ---------------- bf16 GEMM: C = A(MxK) * B^T (B stored NxK) ----------------
// T2 XOR-swizzled LDS (byte ^= (row&7)<<4): linear gload_lds dest + inverse-swizzled
// global source + swizzled ds_read (rule #21). Kills the 8-way read conflict.
// MODE 1: bf16 out = gelu(acc+bias). MODE 2: bf16 out = acc+bias.
// MODE 3 (qkv): cols<2048 -> outB stride 2048 (q,k); cols>=2048 -> vT[w*16+h][d][kv].
template <int MODE>
__global__ __launch_bounds__(256, 2) void gemm_bt(
    const uint16_t* __restrict__ A, const uint16_t* __restrict__ Bw,
    const float* __restrict__ bias, uint16_t* __restrict__ outB,
    uint16_t* __restrict__ vTout, int M, int N, int K) {
  __shared__ __align__(16) uint16_t As[4096];  // 128 rows x 32 k (swizzled)
  __shared__ __align__(16) uint16_t Bs[4096];
  const int tid = threadIdx.x;
  const int nTn = N >> 7;
  const int bm = blockIdx.x / nTn;
  const int bn = blockIdx.x - bm * nTn;
  const int lane = tid & 63;
  const int wid = tid >> 6;
  const int wr = (wid >> 1) * 64;
  const int wc = (wid & 1) * 64;

  // inverse-swizzle the SOURCE: thread t's linear LDS slot t*16B holds logical
  // (lrow, sk): lrow = (t>>2) ^ bit2(t>>2); sk = ((t&3) ^ lrow) & 3.
  const int rphys = tid >> 2;
  const int lrow = rphys ^ ((rphys >> 2) & 1);
  const int sk = (((tid & 3) ^ lrow) & 3) * 8;
  const size_t aBase = (size_t)(bm * 128 + lrow) * K + sk;
  const size_t bBase = (size_t)(bn * 128 + lrow) * K + sk;
  const size_t half = (size_t)64 * K;
  uint16_t* lA = As + (size_t)wid * 512;  // wave-uniform base; HW adds lane*16B
  uint16_t* lB = Bs + (size_t)wid * 512;

  const f32x4 fzero = {0.f, 0.f, 0.f, 0.f};
  f32x4 acc[4][4];
#pragma unroll
  for (int m = 0; m < 4; ++m)
#pragma unroll
    for (int n = 0; n < 4; ++n) acc[m][n] = fzero;

  const int r16 = lane & 15;
  const int koff = (lane >> 4) * 8;
  const int rx = (r16 & 7) << 3;  // read-side XOR (elem bits 3-5 = byte bits 4-6)

  for (int kt = 0; kt < K; kt += 32) {
    GL2LDS16(A + aBase + kt, lA);
    GL2LDS16(A + aBase + kt + half, lA + 2048);
    GL2LDS16(Bw + bBase + kt, lB);
    GL2LDS16(Bw + bBase + kt + half, lB + 2048);
    __syncthreads();
    s16x8 af[4], bfr[4];
#pragma unroll
    for (int m = 0; m < 4; ++m)
      af[m] = *(const s16x8*)(As + (((wr + m * 16 + r16) * 32 + koff) ^ rx));
#pragma unroll
    for (int n = 0; n < 4; ++n)
      bfr[n] = *(const s16x8*)(Bs + (((wc + n * 16 + r16) * 32 + koff) ^ rx));
#pragma unroll
    for (int m = 0; m < 4; ++m)
#pragma unroll
      for (int n = 0; n < 4; ++n)
        acc[m][n] = mfma16(af[m], bfr[n], acc[m][n]);
    __syncthreads();
  }

  const int row0 = bm * 128 + wr + (lane >> 4) * 4;
  const int col0 = bn * 128 + wc + r16;
  if (MODE == 3 && bn >= 16) {
    // V columns -> transposed write vT[(w*16+h)][d][kv], 4 consecutive kv per lane
#pragma unroll
    for (int m = 0; m < 4; ++m) {
      const int tokb = row0 + m * 16;            // kv0 = tokb&255 (mult of 4), w = tokb>>8
#pragma unroll
      for (int n = 0; n < 4; ++n) {
        const int col = col0 + n * 16;
        const float bv = bias[col];
        const int hh = (col - 2048) >> 6, dd = (col - 2048) & 63;
        ushort4 pk;
        pk.x = f2bf(acc[m][n][0] + bv);
        pk.y = f2bf(acc[m][n][1] + bv);
        pk.z = f2bf(acc[m][n][2] + bv);
        pk.w = f2bf(acc[m][n][3] + bv);
        *(ushort4*)(vTout + ((size_t)((tokb >> 8) * 16 + hh) * 64 + dd) * 256 + (tokb & 255)) = pk;
      }
    }
    return;
  }
  const int ostride = (MODE == 3) ? 2048 : N;
#pragma unroll
  for (int m = 0; m < 4; ++m) {
#pragma unroll
    for (int n = 0; n < 4; ++n) {
      const int col = col0 + n * 16;
      const float bv = bias[col];
#pragma unroll
      for (int r = 0; r < 4; ++r) {
        const int row = row0 + m * 16 + r;
        float v = acc[m][n][r] + bv;
        if (MODE == 1) v = 0.5f * v * (1.f + erff(v * 0.70710678f));
        outB[(size_t)row * ostride + col] = f2bf(v);
      }
    }
  }
}

// ---------------- in-place l2 normalize of bf16 q,k rows (64-dim), stride 2048 ----------
__global__ __launch_bounds__(256) void l2norm_kernel(uint16_t* __restrict__ qkB) {
  const int t = threadIdx.x;
  const int gg = t >> 4, sub = t & 15;
  const int R = blockIdx.x * 16 + gg;  // rows over 16384 tokens * {q,k} * 16 heads
  const int tok = R >> 5, rem = R & 31;
  const int qksel = rem >> 4, hh = rem & 15;
  uint16_t* p = qkB + (size_t)tok * 2048 + qksel * 1024 + hh * 64 + sub * 4;
  const ushort4 u = *(const ushort4*)p;
  float a = bf2f(u.x), b = bf2f(u.y), c = bf2f(u.z), d = bf2f(u.w);
  float ss = a * a + b * b + c * c + d * d;
#pragma unroll
  for (int m = 1; m < 16; m <<= 1) ss += __shfl_xor(ss, m);
  const float inv = 1.f / fmaxf(sqrtf(ss), 1e-12f);
  ushort4 o;
  o.x = f2bf(a * inv); o.y = f2bf(b * inv); o.z = f2bf(c * inv); o.w = f2bf(d * inv);
  *(ushort4*)p = o;
}

// ---------------- MFMA windowed attention (spill-free: 2 M-frags/wave) ----------------
// Block = 4 waves = one (window, head, q-half). Wave wid owns 32 q rows.
// Grid = 64 windows * 16 heads * 2 halves = 2048 blocks.
__global__ __launch_bounds__(256, 2) void attn_mfma(
    const uint16_t* __restrict__ qk, const uint16_t* __restrict__ vT,
    const float* __restrict__ logit_scale, const float* __restrict__ biasH,
    uint16_t* __restrict__ outB) {
  __shared__ __align__(16) uint16_t Ks[64 * 72];
  __shared__ __align__(16) uint16_t Vs[64 * 72];
  __shared__ __align__(16) uint16_t Ps[4][32 * 72];
  __shared__ float bsm[512];
  const int bid = blockIdx.x;
  const int w = bid >> 5;
  const int h = (bid >> 1) & 15;
  const int qbase = (bid & 1) * 128;
  const int tid = threadIdx.x;
  const int lane = tid & 63;
  const int wid = tid >> 6;
  const int q15 = lane & 15;
  const int g = lane >> 4;
  const bool lastwin = ((w & 31) == 31);
  const float scale = __expf(fminf(logit_scale[h], 4.60517018599f));  // ln(100)

  bsm[tid] = biasH[h * 512 + tid];
  bsm[tid + 256] = biasH[h * 512 + 256 + tid];

  // Q A-fragments: rows qbase + wid*32 + m*16 + q15, k-elems ks*32 + g*8 + e
  s16x8 qf[2][2];
  {
    const uint16_t* qb = qk + (size_t)(w * 256 + qbase + wid * 32 + q15) * 2048 + h * 64 + g * 8;
#pragma unroll
    for (int m = 0; m < 2; ++m)
#pragma unroll
      for (int ks = 0; ks < 2; ++ks)
        qf[m][ks] = *(const s16x8*)(qb + (size_t)(m * 16) * 2048 + ks * 32);
  }

  // staging addresses (2 x 16B units per thread for each of K, V^T)
  const int r0 = tid >> 3, c8 = (tid & 7) * 8;
  const uint16_t* kg = qk + (size_t)(w * 256 + r0) * 2048 + 1024 + h * 64 + c8;
  const uint16_t* vg = vT + ((size_t)(w * 16 + h) * 64 + r0) * 256 + c8;
  uint16_t* kd0 = Ks + r0 * 72 + c8;
  uint16_t* kd1 = Ks + (r0 + 32) * 72 + c8;
  uint16_t* vd0 = Vs + r0 * 72 + c8;
  uint16_t* vd1 = Vs + (r0 + 32) * 72 + c8;

  // chunk 0 stage
  s16x8 stK0 = *(const s16x8*)(kg);
  s16x8 stK1 = *(const s16x8*)(kg + 32 * 2048);
  s16x8 stV0 = *(const s16x8*)(vg);
  s16x8 stV1 = *(const s16x8*)(vg + 32 * 256);
  *(s16x8*)kd0 = stK0; *(s16x8*)kd1 = stK1;
  *(s16x8*)vd0 = stV0; *(s16x8*)vd1 = stV1;

  const f32x4 fzero = {0.f, 0.f, 0.f, 0.f};
  f32x4 o[2][4];
  float mrun[2][4], lrun[2][4];
#pragma unroll
  for (int m = 0; m < 2; ++m)
#pragma unroll
    for (int n = 0; n < 4; ++n) o[m][n] = fzero;
#pragma unroll
  for (int m = 0; m < 2; ++m)
#pragma unroll
    for (int r = 0; r < 4; ++r) { mrun[m][r] = -1e30f; lrun[m][r] = 0.f; }

  __syncthreads();

  for (int c = 0; c < 4; ++c) {
    if (c < 3) {  // T14: issue next-chunk loads early, write after barrier
      stK0 = *(const s16x8*)(kg + (size_t)(c + 1) * 64 * 2048);
      stK1 = *(const s16x8*)(kg + (size_t)(c + 1) * 64 * 2048 + 32 * 2048);
      stV0 = *(const s16x8*)(vg + (c + 1) * 64);
      stV1 = *(const s16x8*)(vg + (c + 1) * 64 + 32 * 256);
    }
    // K B-frags: col kv = n*16+q15, k-elems d = ks*32+g*8+e
    s16x8 kf[4][2];
#pragma unroll
    for (int n = 0; n < 4; ++n)
#pragma unroll
      for (int ks = 0; ks < 2; ++ks)
        kf[n][ks] = *(const s16x8*)(Ks + (n * 16 + q15) * 72 + ks * 32 + g * 8);

    f32x4 s[2][4];
#pragma unroll
    for (int m = 0; m < 2; ++m)
#pragma unroll
      for (int n = 0; n < 4; ++n) {
        f32x4 a = fzero;
        a = mfma16(qf[m][0], kf[n][0], a);
        a = mfma16(qf[m][1], kf[n][1], a);
        s[m][n] = a;
      }

    // scale + bias + shift-mask  (i row, j col within window)
#pragma unroll
    for (int m = 0; m < 2; ++m)
#pragma unroll
      for (int n = 0; n < 4; ++n)
#pragma unroll
        for (int r = 0; r < 4; ++r) {
          const int i = qbase + wid * 32 + m * 16 + g * 4 + r;
          const int j = c * 64 + n * 16 + q15;
          float sv = s[m][n][r] * scale + bsm[i - j + 255];
          if (lastwin && ((i >> 7) != (j >> 7))) sv -= 100.f;
          s[m][n][r] = sv;
        }

    // online softmax per row (m,r); row replicated across 16 lanes sharing g
#pragma unroll
    for (int m = 0; m < 2; ++m)
#pragma unroll
      for (int r = 0; r < 4; ++r) {
        float cm = fmaxf(fmaxf(s[m][0][r], s[m][1][r]), fmaxf(s[m][2][r], s[m][3][r]));
        cm = fmaxf(cm, __shfl_xor(cm, 1));
        cm = fmaxf(cm, __shfl_xor(cm, 2));
        cm = fmaxf(cm, __shfl_xor(cm, 4));
        cm = fmaxf(cm, __shfl_xor(cm, 8));
        const float mn = fmaxf(mrun[m][r], cm);
        const float corr = __expf(mrun[m][r] - mn);
        mrun[m][r] = mn;
        float rs = 0.f;
#pragma unroll
        for (int n = 0; n < 4; ++n) {
          const float p = __expf(s[m][n][r] - mn);
          s[m][n][r] = p;
          rs += p;
        }
        rs += __shfl_xor(rs, 1);
        rs += __shfl_xor(rs, 2);
        rs += __shfl_xor(rs, 4);
        rs += __shfl_xor(rs, 8);
        lrun[m][r] = lrun[m][r] * corr + rs;
#pragma unroll
        for (int nf = 0; nf < 4; ++nf) o[m][nf][r] *= corr;
      }

    // P -> per-wave LDS (bf16), then read as A-frags
    uint16_t* pw = Ps[wid];
#pragma unroll
    for (int m = 0; m < 2; ++m)
#pragma unroll
      for (int r = 0; r < 4; ++r)
#pragma unroll
        for (int n = 0; n < 4; ++n)
          pw[(m * 16 + g * 4 + r) * 72 + n * 16 + q15] = f2bf(s[m][n][r]);

    s16x8 pf[2][2], vf[4][2];
#pragma unroll
    for (int m = 0; m < 2; ++m)
#pragma unroll
      for (int ks = 0; ks < 2; ++ks)
        pf[m][ks] = *(const s16x8*)(pw + (m * 16 + q15) * 72 + ks * 32 + g * 8);
#pragma unroll
    for (int nf = 0; nf < 4; ++nf)
#pragma unroll
      for (int ks = 0; ks < 2; ++ks)
        vf[nf][ks] = *(const s16x8*)(Vs + (nf * 16 + q15) * 72 + ks * 32 + g * 8);
#pragma unroll
    for (int m = 0; m < 2; ++m)
#pragma unroll
      for (int nf = 0; nf < 4; ++nf) {
        o[m][nf] = mfma16(pf[m][0], vf[nf][0], o[m][nf]);
        o[m][nf] = mfma16(pf[m][1], vf[nf][1], o[m][nf]);
      }
    __syncthreads();
    if (c < 3) {
      *(s16x8*)kd0 = stK0; *(s16x8*)kd1 = stK1;
      *(s16x8*)vd0 = stV0; *(s16x8*)vd1 = stV1;
      __syncthreads();
    }
  }

  // epilogue: O /= l, store bf16
  uint16_t* ob = outB + (size_t)(w * 256 + qbase + wid * 32) * 1024 + h * 64;
#pragma unroll
  for (int m = 0; m < 2; ++m)
#pragma unroll
    for (int r = 0; r < 4; ++r) {
      const float inv = 1.f / lrun[m][r];
#pragma unroll
      for (int nf = 0; nf < 4; ++nf)
        ob[(size_t)(m * 16 + g * 4 + r) * 1024 + nf * 16 + q15] = f2bf(o[m][nf][r] * inv);
    }
}

// ---------------- LayerNorm + residual (bf16 src) ----------------
// FIRST=1: src in shifted window domain -> un-shift (+S); write fp32 out + bf16 copy.
// FIRST=0: resid and outF may alias (row-wise read-then-write).
template <int FIRST>
__global__ __launch_bounds__(256) void ln_kernel(
    const uint16_t* __restrict__ src, const float* resid,
    const float* __restrict__ gam, const float* __restrict__ bet,
    float* outF, uint16_t* __restrict__ outB) {
  const int tok = blockIdx.x;
  const int t = threadIdx.x;
  size_t srow;
  if (FIRST) {
    const int b = tok >> 13, l = tok & 8191;
    srow = (size_t)(b * 8192 + ((l - 128) & 8191)) * 1024;  // roll(+S)
  } else {
    srow = (size_t)tok * 1024;
  }
  const ushort4 u = *(const ushort4*)(src + srow + t * 4);
  const float vv[4] = {bf2f(u.x), bf2f(u.y), bf2f(u.z), bf2f(u.w)};
  float s1 = vv[0] + vv[1] + vv[2] + vv[3];
  float s2 = vv[0] * vv[0] + vv[1] * vv[1] + vv[2] * vv[2] + vv[3] * vv[3];
#pragma unroll
  for (int m = 1; m < 64; m <<= 1) {
    s1 += __shfl_xor(s1, m);
    s2 += __shfl_xor(s2, m);
  }
  __shared__ float r1[4], r2[4];
  const int wid = t >> 6;
  if ((t & 63) == 0) { r1[wid] = s1; r2[wid] = s2; }
  __syncthreads();
  s1 = r1[0] + r1[1] + r1[2] + r1[3];
  s2 = r2[0] + r2[1] + r2[2] + r2[3];
  const float mu = s1 * 0.0009765625f;
  const float var = s2 * 0.0009765625f - mu * mu;
  const float rs = rsqrtf(var + 1e-5f);
  const float4 rv = *(const float4*)(resid + (size_t)tok * 1024 + t * 4);
  const float rr[4] = {rv.x, rv.y, rv.z, rv.w};
#pragma unroll
  for (int e = 0; e < 4; ++e) {
    const int c = t * 4 + e;
    const float y = (vv[e] - mu) * rs * gam[c] + bet[c];
    const float xo = rr[e] + y;
    outF[(size_t)tok * 1024 + c] = xo;
    if (FIRST) outB[(size_t)tok * 1024 + c] = f2bf(xo);
  }
}

// ---------------- launch ----------------
extern "C" void kernel_launch(void* const* d_in, const int* in_sizes, int n_in,
                              void* d_out, int out_size, void* d_ws, size_t ws_size,
                              hipStream_t stream) {
  const float* x = (const float*)d_in[0];
  const float* qkv_w = (const float*)d_in[1];
  const float* q_bias = (const float*)d_in[2];
  const float* v_bias = (const float*)d_in[3];
  const float* logit_sc = (const float*)d_in[4];
  const float* cpb_w1 = (const float*)d_in[5];
  const float* cpb_b1 = (const float*)d_in[6];
  const float* cpb_w2 = (const float*)d_in[7];
  const float* proj_w = (const float*)d_in[8];
  const float* proj_b = (const float*)d_in[9];
  const float* n1g = (const float*)d_in[10];
  const float* n1b = (const float*)d_in[11];
  const float* fc1_w = (const float*)d_in[12];
  const float* fc1_b = (const float*)d_in[13];
  const float* fc2_w = (const float*)d_in[14];
  const float* fc2_b = (const float*)d_in[15];
  const float* n2g = (const float*)d_in[16];
  const float* n2b = (const float*)d_in[17];

  // Workspace map (phase-aliased, peak ~193 MB). Lifetimes:
  //  [0,64M)    qkB (B-D)      -> out2b [0,32M) (E-F) -> hbuf [0,64M) (G-H)
  //  [64,96M)   vT (B-D)       -> x1b (F-I)
  //  [96,128M)  xw (A-B)       -> attnout (D-E)
  //  [128,160M) tmpb (H-I)
  //  [160M+)    bf16 weights + tables
  //  d_out doubles as fp32 x1 (written by ln1, read+rewritten by ln2)
  char* ws = (char*)d_ws;
  uint16_t* qkB     = (uint16_t*)(ws + 0);
  uint16_t* out2b   = (uint16_t*)(ws + 0);
  uint16_t* hbuf    = (uint16_t*)(ws + 0);
  uint16_t* vT      = (uint16_t*)(ws + 67108864);
  uint16_t* x1b     = (uint16_t*)(ws + 67108864);
  uint16_t* xw      = (uint16_t*)(ws + 100663296);
  uint16_t* attnout = (uint16_t*)(ws + 100663296);
  uint16_t* tmpb    = (uint16_t*)(ws + 134217728);
  uint16_t* wqkv    = (uint16_t*)(ws + 167772160);
  uint16_t* wproj   = (uint16_t*)(ws + 174063616);
  uint16_t* wfc1    = (uint16_t*)(ws + 176160768);
  uint16_t* wfc2    = (uint16_t*)(ws + 184549376);
  float* qkvb       = (float*)(ws + 192937984);
  float* biasH      = (float*)(ws + 192950272);
  float* outp = (float*)d_out;

  if (ws_size < 192983040ULL) {  // diagnosable sentinel instead of silent zero
    fill_kernel<<<(out_size + 255) / 256, 256, 0, stream>>>(outp, out_size);
    return;
  }

  cpb_kernel<<<32, 256, 0, stream>>>(cpb_w1, cpb_b1, cpb_w2, biasH);
  qkvbias_kernel<<<12, 256, 0, stream>>>(q_bias, v_bias, qkvb);
  cvt_kernel<<<3072, 256, 0, stream>>>(qkv_w, wqkv, 786432);
  cvt_kernel<<<1024, 256, 0, stream>>>(proj_w, wproj, 262144);
  cvt_kernel<<<4096, 256, 0, stream>>>(fc1_w, wfc1, 1048576);
  cvt_kernel<<<4096, 256, 0, stream>>>(fc2_w, wfc2, 1048576);
  shiftcvt_kernel<<<16384, 256, 0, stream>>>(x, xw);

  gemm_bt<3><<<3072, 256, 0, stream>>>(xw, wqkv, qkvb, qkB, vT, 16384, 3072, 1024);
  l2norm_kernel<<<32768, 256, 0, stream>>>(qkB);
  attn_mfma<<<2048, 256, 0, stream>>>(qkB, vT, logit_sc, biasH, attnout);
  gemm_bt<2><<<1024, 256, 0, stream>>>(attnout, wproj, proj_b, out2b, nullptr, 16384, 1024, 1024);
  ln_kernel<1><<<16384, 256, 0, stream>>>(out2b, x, n1g, n1b, outp, x1b);
  // MLP in two M=8192 passes to keep hidden buffer at 64 MB
  for (int p = 0; p < 2; ++p) {
    const size_t ro = (size_t)p * 8192;
    gemm_bt<1><<<2048, 256, 0, stream>>>(x1b + ro * 1024, wfc1, fc1_b, hbuf, nullptr, 8192, 4096, 1024);
    gemm_bt<2><<<512, 256, 0, stream>>>(hbuf, wfc2, fc2_b, tmpb + ro * 1024, nullptr, 8192, 1024, 4096);
  }
  ln_kernel<0><<<16384, 256, 0, stream>>>(tmpb, outp, n2g, n2b, outp, nullptr);
}